// Round 3
// baseline (439.739 us; speedup 1.0000x reference)
//
#include <hip/hip_runtime.h>

typedef unsigned short u16;
typedef __attribute__((ext_vector_type(4))) float f4;
typedef __attribute__((ext_vector_type(8))) short s8v;    // 8 x bf16 MFMA frag (4 VGPRs)
typedef __attribute__((ext_vector_type(4))) unsigned short u16x4;

#define DEVINL __device__ __forceinline__

DEVINL float b2f(u16 u) { union { unsigned i; float f; } x; x.i = ((unsigned)u) << 16; return x.f; }
DEVINL u16 f2b(float f) {
  union { float f; unsigned i; } x; x.f = f;
  unsigned r = 0x7FFFu + ((x.i >> 16) & 1u);
  return (u16)((x.i + r) >> 16);
}

#define GLD_LDS16(g, l)                                                        \
  __builtin_amdgcn_global_load_lds((__attribute__((address_space(1))) void*)(g), \
                                   (__attribute__((address_space(3))) void*)(l), 16, 0, 0)

// ---------------- transpose + fp32->bf16 cast: out[C,R] = cast(in[R,C]^T) ----------------
__global__ __launch_bounds__(256) void k_transpose(const float* __restrict__ in,
                                                   u16* __restrict__ out, int R, int C) {
  __shared__ float t[32][33];
  int tx = threadIdx.x & 31, ty = threadIdx.x >> 5;
  int c0 = blockIdx.x * 32, r0 = blockIdx.y * 32;
#pragma unroll
  for (int i = 0; i < 32; i += 8)
    t[ty + i][tx] = in[(long)(r0 + ty + i) * C + (c0 + tx)];
  __syncthreads();
#pragma unroll
  for (int i = 0; i < 32; i += 8)
    out[(long)(c0 + ty + i) * R + (r0 + tx)] = f2b(t[tx][ty + i]);
}

// ---------------- bf16 V transpose: v [B,S,H,D] -> vt [B,H,D,S] ----------------
__global__ __launch_bounds__(256) void k_vtrans(const u16* __restrict__ v, u16* __restrict__ vt) {
  __shared__ u16 t[64][72];
  int bh = blockIdx.x, b = bh >> 4, h = bh & 15;
  int s0 = blockIdx.y * 64;
  int tid = threadIdx.x;
#pragma unroll
  for (int p = 0; p < 2; ++p) {
    int idx = p * 256 + tid;
    int sl = idx >> 3, c8 = (idx & 7) * 8;
    *(s8v*)(&t[sl][c8]) = *(const s8v*)(v + (((long)(b * 1024 + s0 + sl) * 16 + h) * 64) + c8);
  }
  __syncthreads();
#pragma unroll
  for (int p = 0; p < 2; ++p) {
    int idx = p * 256 + tid;
    int d = idx >> 3, c8 = (idx & 7) * 8;
    s8v o;
#pragma unroll
    for (int e = 0; e < 8; ++e) o[e] = (short)t[c8 + e][d];
    *(s8v*)(vt + ((long)bh * 64 + d) * 1024 + s0 + c8) = o;
  }
}

// ---------------- LayerNorm over E=1024, one row per block, bf16 out ----------------
__global__ __launch_bounds__(256) void k_layernorm(const float* __restrict__ x,
                                                   const float* __restrict__ g,
                                                   const float* __restrict__ be,
                                                   u16* __restrict__ out) {
  long row = blockIdx.x;
  int tid = threadIdx.x;
  f4 v = ((const f4*)(x + row * 1024))[tid];
  float s = v[0] + v[1] + v[2] + v[3];
  float s2 = v[0] * v[0] + v[1] * v[1] + v[2] * v[2] + v[3] * v[3];
#pragma unroll
  for (int off = 32; off > 0; off >>= 1) {
    s += __shfl_down(s, off, 64);
    s2 += __shfl_down(s2, off, 64);
  }
  __shared__ float red[8];
  int wv = tid >> 6, ln = tid & 63;
  if (ln == 0) { red[wv] = s; red[4 + wv] = s2; }
  __syncthreads();
  s = red[0] + red[1] + red[2] + red[3];
  s2 = red[4] + red[5] + red[6] + red[7];
  float mean = s * (1.0f / 1024.0f);
  float var = s2 * (1.0f / 1024.0f) - mean * mean;
  float rs = rsqrtf(var + 1e-5f);
  f4 gg = ((const f4*)g)[tid];
  f4 bb = ((const f4*)be)[tid];
  u16x4 o;
#pragma unroll
  for (int i = 0; i < 4; ++i) o[i] = f2b((v[i] - mean) * rs * gg[i] + bb[i]);
  ((u16x4*)(out + row * 1024))[tid] = o;
}

// ---------------- QKV: [131072,64] @ [64,64] x3, MFMA 16x16x32 bf16 ----------------
__global__ __launch_bounds__(256) void k_qkv(const u16* __restrict__ nx, const u16* __restrict__ WqT,
                                             const u16* __restrict__ WkT, const u16* __restrict__ WvT,
                                             u16* __restrict__ q, u16* __restrict__ k,
                                             u16* __restrict__ v) {
  int tid = threadIdx.x, lane = tid & 63, wave = tid >> 6;
  int quad = lane >> 4, l16 = lane & 15;
  long rbase = (long)blockIdx.x * 64 + wave * 16;
  s8v a0 = *(const s8v*)(nx + (rbase + l16) * 64 + quad * 8);
  s8v a1 = *(const s8v*)(nx + (rbase + l16) * 64 + 32 + quad * 8);
  const u16* Ws[3] = {WqT, WkT, WvT};
  u16* Os[3] = {q, k, v};
#pragma unroll
  for (int t = 0; t < 3; ++t) {
#pragma unroll
    for (int j = 0; j < 4; ++j) {
      s8v b0 = *(const s8v*)(Ws[t] + (j * 16 + l16) * 64 + quad * 8);
      s8v b1 = *(const s8v*)(Ws[t] + (j * 16 + l16) * 64 + 32 + quad * 8);
      f4 acc = {0.f, 0.f, 0.f, 0.f};
      acc = __builtin_amdgcn_mfma_f32_16x16x32_bf16(a0, b0, acc, 0, 0, 0);
      acc = __builtin_amdgcn_mfma_f32_16x16x32_bf16(a1, b1, acc, 0, 0, 0);
#pragma unroll
      for (int r = 0; r < 4; ++r)
        Os[t][(rbase + quad * 4 + r) * 64 + j * 16 + l16] = f2b(acc[r]);
    }
  }
}

// ---------------- MFMA flash attention (causal) ----------------
__global__ __launch_bounds__(256) void k_attn_mfma(const u16* __restrict__ q,
                                                   const u16* __restrict__ kk,
                                                   const u16* __restrict__ vt,
                                                   u16* __restrict__ o) {
  constexpr int LDK = 72;
  __shared__ u16 Ks[64 * LDK];
  __shared__ u16 Vt[64 * LDK];
  __shared__ u16 Ps[4][16 * LDK];
  int tid = threadIdx.x, lane = tid & 63, wave = tid >> 6;
  int quad = lane >> 4, l16 = lane & 15;
  int b = blockIdx.x >> 4, h = blockIdx.x & 15;
  int qi = (int)gridDim.y - 1 - (int)blockIdx.y;
  int q0 = qi * 64 + wave * 16;

  const u16* qp = q + (((long)(b * 1024 + q0 + l16)) * 16 + h) * 64;
  s8v aq0 = *(const s8v*)(qp + quad * 8);
  s8v aq1 = *(const s8v*)(qp + 32 + quad * 8);

  f4 O[4];
  float m_[4], l_[4];
#pragma unroll
  for (int jd = 0; jd < 4; ++jd) O[jd] = f4{0.f, 0.f, 0.f, 0.f};
#pragma unroll
  for (int r = 0; r < 4; ++r) { m_[r] = -__builtin_inff(); l_[r] = 0.f; }

  for (int kt = 0; kt <= qi; ++kt) {
    __syncthreads();
#pragma unroll
    for (int p = 0; p < 2; ++p) {
      int idx = p * 256 + tid;
      int row = idx >> 3, c8 = (idx & 7) * 8;
      *(s8v*)(Ks + row * LDK + c8) =
          *(const s8v*)(kk + (((long)(b * 1024 + kt * 64 + row)) * 16 + h) * 64 + c8);
      *(s8v*)(Vt + row * LDK + c8) =
          *(const s8v*)(vt + ((long)blockIdx.x * 64 + row) * 1024 + kt * 64 + c8);
    }
    __syncthreads();

    f4 sf[4];
#pragma unroll
    for (int jn = 0; jn < 4; ++jn) {
      s8v b0 = *(const s8v*)(Ks + (jn * 16 + l16) * LDK + quad * 8);
      s8v b1 = *(const s8v*)(Ks + (jn * 16 + l16) * LDK + 32 + quad * 8);
      f4 acc = f4{0.f, 0.f, 0.f, 0.f};
      acc = __builtin_amdgcn_mfma_f32_16x16x32_bf16(aq0, b0, acc, 0, 0, 0);
      acc = __builtin_amdgcn_mfma_f32_16x16x32_bf16(aq1, b1, acc, 0, 0, 0);
      sf[jn] = acc;
    }
    bool diag = (kt == qi);
    float rm[4];
#pragma unroll
    for (int r = 0; r < 4; ++r) rm[r] = -__builtin_inff();
#pragma unroll
    for (int jn = 0; jn < 4; ++jn)
#pragma unroll
      for (int r = 0; r < 4; ++r) {
        float v = sf[jn][r] * 0.03125f;
        if (diag && (jn * 16 + l16 > wave * 16 + quad * 4 + r)) v = -__builtin_inff();
        sf[jn][r] = v;
        rm[r] = fmaxf(rm[r], v);
      }
#pragma unroll
    for (int off = 1; off < 16; off <<= 1)
#pragma unroll
      for (int r = 0; r < 4; ++r) rm[r] = fmaxf(rm[r], __shfl_xor(rm[r], off, 64));
    float alpha[4], rs[4];
#pragma unroll
    for (int r = 0; r < 4; ++r) {
      float mn = fmaxf(m_[r], rm[r]);
      alpha[r] = __expf(m_[r] - mn);
      m_[r] = mn;
      rs[r] = 0.f;
    }
#pragma unroll
    for (int jn = 0; jn < 4; ++jn)
#pragma unroll
      for (int r = 0; r < 4; ++r) {
        float p = __expf(sf[jn][r] - m_[r]);
        rs[r] += p;
        Ps[wave][(quad * 4 + r) * LDK + jn * 16 + l16] = f2b(p);
      }
#pragma unroll
    for (int off = 1; off < 16; off <<= 1)
#pragma unroll
      for (int r = 0; r < 4; ++r) rs[r] += __shfl_xor(rs[r], off, 64);
#pragma unroll
    for (int r = 0; r < 4; ++r) l_[r] = l_[r] * alpha[r] + rs[r];
#pragma unroll
    for (int jd = 0; jd < 4; ++jd)
#pragma unroll
      for (int r = 0; r < 4; ++r) O[jd][r] *= alpha[r];
    asm volatile("s_waitcnt lgkmcnt(0)" ::: "memory");
    s8v p0 = *(const s8v*)(&Ps[wave][l16 * LDK + quad * 8]);
    s8v p1 = *(const s8v*)(&Ps[wave][l16 * LDK + 32 + quad * 8]);
#pragma unroll
    for (int jd = 0; jd < 4; ++jd) {
      s8v b0 = *(const s8v*)(Vt + (jd * 16 + l16) * LDK + quad * 8);
      s8v b1 = *(const s8v*)(Vt + (jd * 16 + l16) * LDK + 32 + quad * 8);
      O[jd] = __builtin_amdgcn_mfma_f32_16x16x32_bf16(p0, b0, O[jd], 0, 0, 0);
      O[jd] = __builtin_amdgcn_mfma_f32_16x16x32_bf16(p1, b1, O[jd], 0, 0, 0);
    }
  }
#pragma unroll
  for (int r = 0; r < 4; ++r) {
    float inv = 1.0f / l_[r];
    u16* op = o + (((long)(b * 1024 + q0 + quad * 4 + r)) * 16 + h) * 64;
#pragma unroll
    for (int jd = 0; jd < 4; ++jd) op[jd * 16 + l16] = f2b(O[jd][r] * inv);
  }
}

// ---------------- 128x128 GEMM, TRIPLE-buffered GLD_LDS, vmcnt(4) barrier ----------------
template <int EPI>
__global__ __launch_bounds__(256) void k_gemm_bt(const u16* __restrict__ A, const u16* __restrict__ BT,
                                                 const float* __restrict__ bias,
                                                 const float* __restrict__ resid,
                                                 void* __restrict__ outp, int M, int N, int K) {
  __shared__ u16 sA[3][128 * 32];
  __shared__ u16 sB[3][128 * 32];
  int tid = threadIdx.x, lane = tid & 63, wave = tid >> 6;
  int quad = lane >> 4, l16 = lane & 15;
  int wm = wave >> 1, wn = wave & 1;
  long bm = blockIdx.x, bn = blockIdx.y;
  int srow = tid >> 2, scol = (tid & 3) * 8;
  const u16* ga = A + (bm * 128 + srow) * (long)K + scol;
  const u16* gb = BT + (bn * 128 + srow) * (long)K + scol;
  int woff = wave * 1024;

  f4 acc[4][4];
#pragma unroll
  for (int i = 0; i < 4; ++i)
#pragma unroll
    for (int j = 0; j < 4; ++j) acc[i][j] = f4{0.f, 0.f, 0.f, 0.f};

#pragma unroll
  for (int t = 0; t < 2; ++t) {
    char* lA = (char*)&sA[t][0] + woff;
    char* lB = (char*)&sB[t][0] + woff;
    GLD_LDS16(ga + t * 32, lA);
    GLD_LDS16(ga + 64 * (long)K + t * 32, lA + 4096);
    GLD_LDS16(gb + t * 32, lB);
    GLD_LDS16(gb + 64 * (long)K + t * 32, lB + 4096);
  }

  int cur = 0;
  for (int k0 = 0; k0 < K; k0 += 32) {
    int k2 = k0 + 64;
    if (k2 < K) {
      asm volatile("s_waitcnt vmcnt(4)\n\ts_barrier" ::: "memory");
      int nb = cur >= 1 ? cur - 1 : 2;
      char* lA = (char*)&sA[nb][0] + woff;
      char* lB = (char*)&sB[nb][0] + woff;
      GLD_LDS16(ga + k2, lA);
      GLD_LDS16(ga + 64 * (long)K + k2, lA + 4096);
      GLD_LDS16(gb + k2, lB);
      GLD_LDS16(gb + 64 * (long)K + k2, lB + 4096);
    } else {
      asm volatile("s_waitcnt vmcnt(0)\n\ts_barrier" ::: "memory");
    }
    const u16* cA = sA[cur];
    const u16* cB = sB[cur];
    s8v aF[4], bF[4];
#pragma unroll
    for (int i = 0; i < 4; ++i)
      aF[i] = *(const s8v*)(cA + (wm * 64 + i * 16 + l16) * 32 + quad * 8);
#pragma unroll
    for (int j = 0; j < 4; ++j)
      bF[j] = *(const s8v*)(cB + (wn * 64 + j * 16 + l16) * 32 + quad * 8);
#pragma unroll
    for (int i = 0; i < 4; ++i)
#pragma unroll
      for (int j = 0; j < 4; ++j)
        acc[i][j] = __builtin_amdgcn_mfma_f32_16x16x32_bf16(aF[i], bF[j], acc[i][j], 0, 0, 0);
    cur = cur < 2 ? cur + 1 : 0;
  }

#pragma unroll
  for (int i = 0; i < 4; ++i) {
#pragma unroll
    for (int j = 0; j < 4; ++j) {
      long row = bm * 128 + wm * 64 + i * 16 + quad * 4;
      int col = (int)bn * 128 + wn * 64 + j * 16 + l16;
      float bcol = bias[col];
#pragma unroll
      for (int r = 0; r < 4; ++r) {
        float val = acc[i][j][r] + bcol;
        if (EPI == 1) {
          ((u16*)outp)[(row + r) * (long)N + col] = f2b(val > 0.f ? val : 0.f);
        } else {
          ((float*)outp)[(row + r) * (long)N + col] = resid[(row + r) * (long)N + col] + val;
        }
      }
    }
  }
}

// ---------------- 256x256 8-phase GEMM, G4 3-bit XOR swizzle ----------------
// A[M,K'] bf16 (row stride lda), BT[N,K'] bf16 (row stride lda). Per block: 256x256
// output over K columns starting at blockIdx.z*K (split-K when gridDim.z=2).
// 512 threads = 8 waves (2M x 4N), per-wave C = 128x64.
// LDS: [buf][mat][half] blocks of [128 rows][64 cols] u16 (128 B rows), 128 KiB total.
// Swizzle (G4, m214-verified): byte ^= ((row&7)<<4) — spreads the 16 rows of a frag
// read across all 8 16B-slots (2 lanes/slot = free). Banks = byte bits 2-6 (row*128
// contributes nothing), so a 3-bit XOR into bits 4-6 is required; the previous 1-bit
// st_16x32 variant left an 8-way conflict (6.3M SQ_LDS_BANK_CONFLICT measured).
// Applied BOTH sides: linear LDS dest + pre-swizzled global source (involution,
// row bits preserved; (row+64)&7==row&7 so both GLDs of a STAGE share one XOR),
// and the same XOR on every ds_read fragment address: slot s in {quad, quad^4} ->
// u16 col 8*(s ^ (l16&7)) (all row bases are multiples of 16, so row&7 == l16&7).
// Staging stream and vmcnt(4)@ph4/ph8 ledger unchanged from round 1.
template <int EPI>
__global__ __launch_bounds__(512) void k_gemm256(const u16* __restrict__ A,
                                                 const u16* __restrict__ BT,
                                                 const float* __restrict__ bias,
                                                 const float* __restrict__ resid,
                                                 void* __restrict__ outp, int M, int N, int K,
                                                 int lda) {
  __shared__ __align__(16) u16 S[65536];  // 128 KiB
  int tid = threadIdx.x, lane = tid & 63, wave = tid >> 6;
  int l16 = lane & 15, quad = lane >> 4;
  int wm = wave >> 2, wn = wave & 3;
  long bm = blockIdx.x, bn = blockIdx.y;
  int z = blockIdx.z;

  // ds_read swizzle: frag k-slot s -> u16 col 8*(s ^ (l16&7))
  int rl = l16 & 7;
  int c0 = 8 * (quad ^ rl);          // frag0: slot = quad
  int c1 = 8 * ((quad ^ 4) ^ rl);    // frag1: slot = quad+4
  int rowA = (wm * 64 + l16) * 64;
  int rowB = (wn * 32 + l16) * 64;

  // staging: thread's 16B lands at phys byte tid*16 (and +8192) of a 16 KB half-block;
  // logical source byte = phys ^ ((phys>>7 & 7)<<4)
  int Lb = tid * 16;
  int Ls = Lb ^ (((Lb >> 7) & 7) << 4);
  int r_ = Ls >> 7, kin = (Ls & 127) >> 1;
  const u16* pA = A + (bm * 256 + r_) * (long)lda + kin + (long)z * K;
  const u16* pB = BT + (bn * 256 + r_) * (long)lda + kin + (long)z * K;

  f4 acc[4][4][2];  // [quadrant mh*2+nh][mi][nj]
#pragma unroll
  for (int q = 0; q < 4; ++q)
#pragma unroll
    for (int mi = 0; mi < 4; ++mi)
#pragma unroll
      for (int nj = 0; nj < 2; ++nj) acc[q][mi][nj] = f4{0.f, 0.f, 0.f, 0.f};
  s8v aF[4][2], bF[2][2][2];

#define BAR asm volatile("s_barrier" ::: "memory")
#define LGK0 asm volatile("s_waitcnt lgkmcnt(0)" ::: "memory")
#define WVM4 asm volatile("s_waitcnt vmcnt(4)" ::: "memory")
#define WVM0 asm volatile("s_waitcnt vmcnt(0)" ::: "memory")

#define STAGE(mat, half, t, buf)                                               \
  do {                                                                         \
    const u16* g_ = ((mat) ? pB : pA) + (long)(half) * 128 * lda + (t) * 64;   \
    char* l_ = ((char*)S) + ((buf) * 32768 + (mat) * 16384 + (half) * 8192) * 2 + wave * 1024; \
    GLD_LDS16(g_, l_);                                                         \
    GLD_LDS16(g_ + 64 * (long)lda, l_ + 8192);                                 \
  } while (0)

#define LDA(buf, mh)                                                           \
  do {                                                                         \
    const u16* p_ = S + (buf) * 32768 + (mh) * 8192 + rowA;                    \
    _Pragma("unroll") for (int mi = 0; mi < 4; ++mi) {                         \
      aF[mi][0] = *(const s8v*)(p_ + mi * 1024 + c0);                          \
      aF[mi][1] = *(const s8v*)(p_ + mi * 1024 + c1);                          \
    }                                                                          \
  } while (0)

#define LDB(buf, nh, set)                                                      \
  do {                                                                         \
    const u16* p_ = S + (buf) * 32768 + 16384 + (nh) * 8192 + rowB;            \
    _Pragma("unroll") for (int nj = 0; nj < 2; ++nj) {                         \
      bF[set][nj][0] = *(const s8v*)(p_ + nj * 1024 + c0);                     \
      bF[set][nj][1] = *(const s8v*)(p_ + nj * 1024 + c1);                     \
    }                                                                          \
  } while (0)

#define MM(q)                                                                  \
  do {                                                                         \
    _Pragma("unroll") for (int mi = 0; mi < 4; ++mi)                           \
        _Pragma("unroll") for (int nj = 0; nj < 2; ++nj) {                     \
      acc[q][mi][nj] = __builtin_amdgcn_mfma_f32_16x16x32_bf16(                \
          aF[mi][0], bF[(q) & 1][nj][0], acc[q][mi][nj], 0, 0, 0);             \
      acc[q][mi][nj] = __builtin_amdgcn_mfma_f32_16x16x32_bf16(                \
          aF[mi][1], bF[(q) & 1][nj][1], acc[q][mi][nj], 0, 0, 0);             \
    }                                                                          \
  } while (0)

#define PHASES(t, LAST)                                                        \
  /* ph1: quad(0,0) tile t (buf0) */                                           \
  LDA(0, 0); LDB(0, 0, 0); STAGE(0, 1, (t) + 1, 1);                            \
  BAR; LGK0; __builtin_amdgcn_s_setprio(1); MM(0); __builtin_amdgcn_s_setprio(0); BAR; \
  /* ph2: quad(0,1) */                                                         \
  LDB(0, 1, 1); STAGE(1, 1, (t) + 1, 1);                                       \
  BAR; LGK0; __builtin_amdgcn_s_setprio(1); MM(1); __builtin_amdgcn_s_setprio(0); BAR; \
  /* ph3: quad(1,0) */                                                         \
  LDA(0, 1); if (!(LAST)) STAGE(0, 0, (t) + 2, 0);                             \
  BAR; LGK0; __builtin_amdgcn_s_setprio(1); MM(2); __builtin_amdgcn_s_setprio(0); BAR; \
  /* ph4: quad(1,1), no new ds_reads */                                        \
  if (!(LAST)) STAGE(1, 0, (t) + 2, 0);                                        \
  __builtin_amdgcn_s_setprio(1); MM(3); __builtin_amdgcn_s_setprio(0);         \
  if (LAST) { WVM0; } else { WVM4; }                                           \
  BAR;                                                                         \
  /* ph5: quad(0,0) tile t+1 (buf1) */                                         \
  LDA(1, 0); LDB(1, 0, 0); if (!(LAST)) STAGE(0, 1, (t) + 2, 0);               \
  BAR; LGK0; __builtin_amdgcn_s_setprio(1); MM(0); __builtin_amdgcn_s_setprio(0); BAR; \
  /* ph6: quad(0,1) */                                                         \
  LDB(1, 1, 1); if (!(LAST)) STAGE(1, 1, (t) + 2, 0);                          \
  BAR; LGK0; __builtin_amdgcn_s_setprio(1); MM(1); __builtin_amdgcn_s_setprio(0); BAR; \
  /* ph7: quad(1,0) */                                                         \
  LDA(1, 1); if (!(LAST)) STAGE(0, 0, (t) + 3, 1);                             \
  BAR; LGK0; __builtin_amdgcn_s_setprio(1); MM(2); __builtin_amdgcn_s_setprio(0); BAR; \
  /* ph8: quad(1,1) */                                                         \
  if (!(LAST)) STAGE(1, 0, (t) + 3, 1);                                        \
  __builtin_amdgcn_s_setprio(1); MM(3); __builtin_amdgcn_s_setprio(0);         \
  if (!(LAST)) { WVM4; BAR; }

  // prologue: 6 half-tiles in stream order
  STAGE(0, 0, 0, 0);  // t0.A0
  STAGE(1, 0, 0, 0);  // t0.B0
  STAGE(0, 1, 0, 0);  // t0.A1
  STAGE(1, 1, 0, 0);  // t0.B1
  STAGE(0, 0, 1, 1);  // t1.A0
  STAGE(1, 0, 1, 1);  // t1.B0
  WVM4; BAR;

  int NI = K >> 7;  // 2 K-tiles (of 64) per iteration
  for (int i = 0; i < NI - 1; ++i) {
    int t = 2 * i;
    PHASES(t, 0);
  }
  {
    int t = 2 * (NI - 1);
    PHASES(t, 1);
  }

#undef PHASES
#undef MM
#undef LDB
#undef LDA
#undef STAGE
#undef WVM0
#undef WVM4
#undef LGK0
#undef BAR

  // epilogue
  float* P0 = (EPI == 0) ? ((float*)outp + (long)z * M * N) : nullptr;
#pragma unroll
  for (int q = 0; q < 4; ++q) {
    int mh = q >> 1, nh = q & 1;
#pragma unroll
    for (int mi = 0; mi < 4; ++mi) {
#pragma unroll
      for (int nj = 0; nj < 2; ++nj) {
        long row = bm * 256 + mh * 128 + wm * 64 + mi * 16 + quad * 4;
        int col = (int)bn * 256 + nh * 128 + wn * 32 + nj * 16 + l16;
        float bcol = 0.f;
        if (EPI != 0) bcol = bias[col];
#pragma unroll
        for (int rr = 0; rr < 4; ++rr) {
          float val = acc[q][mi][nj][rr] + bcol;
          if (EPI == 0) {
            P0[(row + rr) * (long)N + col] = val;
          } else if (EPI == 1) {
            ((u16*)outp)[(row + rr) * (long)N + col] = f2b(val > 0.f ? val : 0.f);
          } else {
            ((float*)outp)[(row + rr) * (long)N + col] =
                resid[(row + rr) * (long)N + col] + val;
          }
        }
      }
    }
  }
}

// ---------------- split-K combine: out = P0 + P1 + bias + resid ----------------
__global__ __launch_bounds__(256) void k_combine(const float* __restrict__ P,
                                                 const float* __restrict__ resid,
                                                 const float* __restrict__ bias,
                                                 float* __restrict__ out) {
  const f4* P0 = (const f4*)P;
  const f4* P1 = P0 + 2097152;  // 8192*1024/4
  const f4* R = (const f4*)resid;
  const f4* Bv = (const f4*)bias;
  f4* O = (f4*)out;
  for (int i = blockIdx.x * 256 + threadIdx.x; i < 2097152; i += 2048 * 256) {
    f4 a = P0[i], b = P1[i], r = R[i], bb = Bv[i & 255];
    O[i] = a + b + r + bb;
  }
}

extern "C" void kernel_launch(void* const* d_in, const int* in_sizes, int n_in, void* d_out,
                              int out_size, void* d_ws, size_t ws_size, hipStream_t stream) {
  const float* x = (const float*)d_in[0];
  const float* Wq = (const float*)d_in[1];
  const float* Wk = (const float*)d_in[2];
  const float* Wv = (const float*)d_in[3];
  const float* Wo = (const float*)d_in[4];
  const float* bo = (const float*)d_in[5];
  const float* W1 = (const float*)d_in[6];
  const float* b1 = (const float*)d_in[7];
  const float* W2 = (const float*)d_in[8];
  const float* b2 = (const float*)d_in[9];
  const float* g1 = (const float*)d_in[10];
  const float* be1 = (const float*)d_in[11];
  const float* g2 = (const float*)d_in[12];
  const float* be2 = (const float*)d_in[13];

  char* ws = (char*)d_ws;
  const size_t MB = 1ull << 20;
  u16* nx = (u16*)(ws + 0);            // 16 MB  LN1 out; reused as attn out; later P0 part
  u16* qb = (u16*)(ws + 16 * MB);      // 16 MB  q; reused as nx2; later P0 part
  u16* kb = (u16*)(ws + 32 * MB);      // 16 MB  later P1 part
  u16* vb = (u16*)(ws + 48 * MB);      // 16 MB  later P1 part
  float* x1 = (float*)(ws + 64 * MB);  // 32 MB  attn-sublayer output (fp32 residual)
  u16* h1 = (u16*)(ws + 96 * MB);      // 64 MB  MLP hidden (after attn)
  u16* vtr = (u16*)(ws + 96 * MB);     // 16 MB  V^T [B,H,D,S]; dead before h1 is written
  u16* WoT = (u16*)(ws + 160 * MB);    // 2 MB
  u16* W1T = (u16*)(ws + 162 * MB);    // 8 MB
  u16* W2T = (u16*)(ws + 170 * MB);    // 8 MB
  u16* WqT = (u16*)(ws + 178 * MB);
  u16* WkT = WqT + 64 * 64;
  u16* WvT = WkT + 64 * 64;
  u16* ob = nx;
  u16* nx2 = qb;
  float* Pk = (float*)ws;  // 2 x 32 MB split-K partials (nx/qb/kb/vb regions, dead by FF2)

  k_transpose<<<dim3(32, 32), 256, 0, stream>>>(Wo, WoT, 1024, 1024);
  k_transpose<<<dim3(128, 32), 256, 0, stream>>>(W1, W1T, 1024, 4096);
  k_transpose<<<dim3(32, 128), 256, 0, stream>>>(W2, W2T, 4096, 1024);
  k_transpose<<<dim3(2, 2), 256, 0, stream>>>(Wq, WqT, 64, 64);
  k_transpose<<<dim3(2, 2), 256, 0, stream>>>(Wk, WkT, 64, 64);
  k_transpose<<<dim3(2, 2), 256, 0, stream>>>(Wv, WvT, 64, 64);

  k_layernorm<<<8192, 256, 0, stream>>>(x, g1, be1, nx);
  k_qkv<<<2048, 256, 0, stream>>>(nx, WqT, WkT, WvT, qb, kb, vb);
  k_vtrans<<<dim3(128, 16), 256, 0, stream>>>(vb, vtr);
  k_attn_mfma<<<dim3(128, 16), 256, 0, stream>>>(qb, kb, vtr, ob);
  k_gemm_bt<2><<<dim3(64, 8), 256, 0, stream>>>(ob, WoT, bo, x, x1, 8192, 1024, 1024);

  k_layernorm<<<8192, 256, 0, stream>>>(x1, g2, be2, nx2);
  k_gemm256<1><<<dim3(32, 16, 1), 512, 0, stream>>>(nx2, W1T, b1, nullptr, h1, 8192, 4096, 1024, 1024);
  k_gemm256<0><<<dim3(32, 4, 2), 512, 0, stream>>>(h1, W2T, nullptr, nullptr, Pk, 8192, 1024, 2048, 4096);
  k_combine<<<2048, 256, 0, stream>>>(Pk, x1, b2, (float*)d_out);
}

// Round 4
// 414.871 us; speedup vs baseline: 1.0599x; 1.0599x over previous
//
#include <hip/hip_runtime.h>

typedef unsigned short u16;
typedef __attribute__((ext_vector_type(4))) float f4;
typedef __attribute__((ext_vector_type(8))) short s8v;    // 8 x bf16 MFMA frag (4 VGPRs)
typedef __attribute__((ext_vector_type(4))) unsigned short u16x4;

#define DEVINL __device__ __forceinline__

DEVINL float b2f(u16 u) { union { unsigned i; float f; } x; x.i = ((unsigned)u) << 16; return x.f; }
DEVINL u16 f2b(float f) {
  union { float f; unsigned i; } x; x.f = f;
  unsigned r = 0x7FFFu + ((x.i >> 16) & 1u);
  return (u16)((x.i + r) >> 16);
}

#define GLD_LDS16(g, l)                                                        \
  __builtin_amdgcn_global_load_lds((__attribute__((address_space(1))) void*)(g), \
                                   (__attribute__((address_space(3))) void*)(l), 16, 0, 0)

// ---------------- transpose + fp32->bf16 cast: out[C,R] = cast(in[R,C]^T) ----------------
__global__ __launch_bounds__(256) void k_transpose(const float* __restrict__ in,
                                                   u16* __restrict__ out, int R, int C) {
  __shared__ float t[32][33];
  int tx = threadIdx.x & 31, ty = threadIdx.x >> 5;
  int c0 = blockIdx.x * 32, r0 = blockIdx.y * 32;
#pragma unroll
  for (int i = 0; i < 32; i += 8)
    t[ty + i][tx] = in[(long)(r0 + ty + i) * C + (c0 + tx)];
  __syncthreads();
#pragma unroll
  for (int i = 0; i < 32; i += 8)
    out[(long)(c0 + ty + i) * R + (r0 + tx)] = f2b(t[tx][ty + i]);
}

// ---------------- bf16 V transpose: v [B,S,H,D] -> vt [B,H,D,S] ----------------
__global__ __launch_bounds__(256) void k_vtrans(const u16* __restrict__ v, u16* __restrict__ vt) {
  __shared__ u16 t[64][72];
  int bh = blockIdx.x, b = bh >> 4, h = bh & 15;
  int s0 = blockIdx.y * 64;
  int tid = threadIdx.x;
#pragma unroll
  for (int p = 0; p < 2; ++p) {
    int idx = p * 256 + tid;
    int sl = idx >> 3, c8 = (idx & 7) * 8;
    *(s8v*)(&t[sl][c8]) = *(const s8v*)(v + (((long)(b * 1024 + s0 + sl) * 16 + h) * 64) + c8);
  }
  __syncthreads();
#pragma unroll
  for (int p = 0; p < 2; ++p) {
    int idx = p * 256 + tid;
    int d = idx >> 3, c8 = (idx & 7) * 8;
    s8v o;
#pragma unroll
    for (int e = 0; e < 8; ++e) o[e] = (short)t[c8 + e][d];
    *(s8v*)(vt + ((long)bh * 64 + d) * 1024 + s0 + c8) = o;
  }
}

// ---------------- LayerNorm over E=1024, one row per block, bf16 out ----------------
__global__ __launch_bounds__(256) void k_layernorm(const float* __restrict__ x,
                                                   const float* __restrict__ g,
                                                   const float* __restrict__ be,
                                                   u16* __restrict__ out) {
  long row = blockIdx.x;
  int tid = threadIdx.x;
  f4 v = ((const f4*)(x + row * 1024))[tid];
  float s = v[0] + v[1] + v[2] + v[3];
  float s2 = v[0] * v[0] + v[1] * v[1] + v[2] * v[2] + v[3] * v[3];
#pragma unroll
  for (int off = 32; off > 0; off >>= 1) {
    s += __shfl_down(s, off, 64);
    s2 += __shfl_down(s2, off, 64);
  }
  __shared__ float red[8];
  int wv = tid >> 6, ln = tid & 63;
  if (ln == 0) { red[wv] = s; red[4 + wv] = s2; }
  __syncthreads();
  s = red[0] + red[1] + red[2] + red[3];
  s2 = red[4] + red[5] + red[6] + red[7];
  float mean = s * (1.0f / 1024.0f);
  float var = s2 * (1.0f / 1024.0f) - mean * mean;
  float rs = rsqrtf(var + 1e-5f);
  f4 gg = ((const f4*)g)[tid];
  f4 bb = ((const f4*)be)[tid];
  u16x4 o;
#pragma unroll
  for (int i = 0; i < 4; ++i) o[i] = f2b((v[i] - mean) * rs * gg[i] + bb[i]);
  ((u16x4*)(out + row * 1024))[tid] = o;
}

// ---------------- QKV: [131072,64] @ [64,64] x3, MFMA 16x16x32 bf16 ----------------
__global__ __launch_bounds__(256) void k_qkv(const u16* __restrict__ nx, const u16* __restrict__ WqT,
                                             const u16* __restrict__ WkT, const u16* __restrict__ WvT,
                                             u16* __restrict__ q, u16* __restrict__ k,
                                             u16* __restrict__ v) {
  int tid = threadIdx.x, lane = tid & 63, wave = tid >> 6;
  int quad = lane >> 4, l16 = lane & 15;
  long rbase = (long)blockIdx.x * 64 + wave * 16;
  s8v a0 = *(const s8v*)(nx + (rbase + l16) * 64 + quad * 8);
  s8v a1 = *(const s8v*)(nx + (rbase + l16) * 64 + 32 + quad * 8);
  const u16* Ws[3] = {WqT, WkT, WvT};
  u16* Os[3] = {q, k, v};
#pragma unroll
  for (int t = 0; t < 3; ++t) {
#pragma unroll
    for (int j = 0; j < 4; ++j) {
      s8v b0 = *(const s8v*)(Ws[t] + (j * 16 + l16) * 64 + quad * 8);
      s8v b1 = *(const s8v*)(Ws[t] + (j * 16 + l16) * 64 + 32 + quad * 8);
      f4 acc = {0.f, 0.f, 0.f, 0.f};
      acc = __builtin_amdgcn_mfma_f32_16x16x32_bf16(a0, b0, acc, 0, 0, 0);
      acc = __builtin_amdgcn_mfma_f32_16x16x32_bf16(a1, b1, acc, 0, 0, 0);
#pragma unroll
      for (int r = 0; r < 4; ++r)
        Os[t][(rbase + quad * 4 + r) * 64 + j * 16 + l16] = f2b(acc[r]);
    }
  }
}

// ---------------- MFMA flash attention (causal) ----------------
__global__ __launch_bounds__(256) void k_attn_mfma(const u16* __restrict__ q,
                                                   const u16* __restrict__ kk,
                                                   const u16* __restrict__ vt,
                                                   u16* __restrict__ o) {
  constexpr int LDK = 72;
  __shared__ u16 Ks[64 * LDK];
  __shared__ u16 Vt[64 * LDK];
  __shared__ u16 Ps[4][16 * LDK];
  int tid = threadIdx.x, lane = tid & 63, wave = tid >> 6;
  int quad = lane >> 4, l16 = lane & 15;
  int b = blockIdx.x >> 4, h = blockIdx.x & 15;
  int qi = (int)gridDim.y - 1 - (int)blockIdx.y;
  int q0 = qi * 64 + wave * 16;

  const u16* qp = q + (((long)(b * 1024 + q0 + l16)) * 16 + h) * 64;
  s8v aq0 = *(const s8v*)(qp + quad * 8);
  s8v aq1 = *(const s8v*)(qp + 32 + quad * 8);

  f4 O[4];
  float m_[4], l_[4];
#pragma unroll
  for (int jd = 0; jd < 4; ++jd) O[jd] = f4{0.f, 0.f, 0.f, 0.f};
#pragma unroll
  for (int r = 0; r < 4; ++r) { m_[r] = -__builtin_inff(); l_[r] = 0.f; }

  for (int kt = 0; kt <= qi; ++kt) {
    __syncthreads();
#pragma unroll
    for (int p = 0; p < 2; ++p) {
      int idx = p * 256 + tid;
      int row = idx >> 3, c8 = (idx & 7) * 8;
      *(s8v*)(Ks + row * LDK + c8) =
          *(const s8v*)(kk + (((long)(b * 1024 + kt * 64 + row)) * 16 + h) * 64 + c8);
      *(s8v*)(Vt + row * LDK + c8) =
          *(const s8v*)(vt + ((long)blockIdx.x * 64 + row) * 1024 + kt * 64 + c8);
    }
    __syncthreads();

    f4 sf[4];
#pragma unroll
    for (int jn = 0; jn < 4; ++jn) {
      s8v b0 = *(const s8v*)(Ks + (jn * 16 + l16) * LDK + quad * 8);
      s8v b1 = *(const s8v*)(Ks + (jn * 16 + l16) * LDK + 32 + quad * 8);
      f4 acc = f4{0.f, 0.f, 0.f, 0.f};
      acc = __builtin_amdgcn_mfma_f32_16x16x32_bf16(aq0, b0, acc, 0, 0, 0);
      acc = __builtin_amdgcn_mfma_f32_16x16x32_bf16(aq1, b1, acc, 0, 0, 0);
      sf[jn] = acc;
    }
    bool diag = (kt == qi);
    float rm[4];
#pragma unroll
    for (int r = 0; r < 4; ++r) rm[r] = -__builtin_inff();
#pragma unroll
    for (int jn = 0; jn < 4; ++jn)
#pragma unroll
      for (int r = 0; r < 4; ++r) {
        float v = sf[jn][r] * 0.03125f;
        if (diag && (jn * 16 + l16 > wave * 16 + quad * 4 + r)) v = -__builtin_inff();
        sf[jn][r] = v;
        rm[r] = fmaxf(rm[r], v);
      }
#pragma unroll
    for (int off = 1; off < 16; off <<= 1)
#pragma unroll
      for (int r = 0; r < 4; ++r) rm[r] = fmaxf(rm[r], __shfl_xor(rm[r], off, 64));
    float alpha[4], rs[4];
#pragma unroll
    for (int r = 0; r < 4; ++r) {
      float mn = fmaxf(m_[r], rm[r]);
      alpha[r] = __expf(m_[r] - mn);
      m_[r] = mn;
      rs[r] = 0.f;
    }
#pragma unroll
    for (int jn = 0; jn < 4; ++jn)
#pragma unroll
      for (int r = 0; r < 4; ++r) {
        float p = __expf(sf[jn][r] - m_[r]);
        rs[r] += p;
        Ps[wave][(quad * 4 + r) * LDK + jn * 16 + l16] = f2b(p);
      }
#pragma unroll
    for (int off = 1; off < 16; off <<= 1)
#pragma unroll
      for (int r = 0; r < 4; ++r) rs[r] += __shfl_xor(rs[r], off, 64);
#pragma unroll
    for (int r = 0; r < 4; ++r) l_[r] = l_[r] * alpha[r] + rs[r];
#pragma unroll
    for (int jd = 0; jd < 4; ++jd)
#pragma unroll
      for (int r = 0; r < 4; ++r) O[jd][r] *= alpha[r];
    asm volatile("s_waitcnt lgkmcnt(0)" ::: "memory");
    s8v p0 = *(const s8v*)(&Ps[wave][l16 * LDK + quad * 8]);
    s8v p1 = *(const s8v*)(&Ps[wave][l16 * LDK + 32 + quad * 8]);
#pragma unroll
    for (int jd = 0; jd < 4; ++jd) {
      s8v b0 = *(const s8v*)(Vt + (jd * 16 + l16) * LDK + quad * 8);
      s8v b1 = *(const s8v*)(Vt + (jd * 16 + l16) * LDK + 32 + quad * 8);
      O[jd] = __builtin_amdgcn_mfma_f32_16x16x32_bf16(p0, b0, O[jd], 0, 0, 0);
      O[jd] = __builtin_amdgcn_mfma_f32_16x16x32_bf16(p1, b1, O[jd], 0, 0, 0);
    }
  }
#pragma unroll
  for (int r = 0; r < 4; ++r) {
    float inv = 1.0f / l_[r];
    u16* op = o + (((long)(b * 1024 + q0 + quad * 4 + r)) * 16 + h) * 64;
#pragma unroll
    for (int jd = 0; jd < 4; ++jd) op[jd * 16 + l16] = f2b(O[jd][r] * inv);
  }
}

// ---------------- 256x256 8-phase GEMM, G4 3-bit XOR swizzle (verified r3: 0 conflicts) ----
// A[M,K'] bf16 (row stride lda), BT[N,K'] bf16. 512 threads = 8 waves (2M x 4N).
// LDS: [buf][mat][half] blocks of [128][64] u16; swizzle byte ^= ((row&7)<<4) both sides.
// vmcnt(4) at ph4/ph8; >=1 barrier between a slot's last ds_read and overwrite issue.
template <int EPI>
__global__ __launch_bounds__(512) void k_gemm256(const u16* __restrict__ A,
                                                 const u16* __restrict__ BT,
                                                 const float* __restrict__ bias,
                                                 const float* __restrict__ resid,
                                                 void* __restrict__ outp, int M, int N, int K,
                                                 int lda) {
  __shared__ __align__(16) u16 S[65536];  // 128 KiB
  int tid = threadIdx.x, lane = tid & 63, wave = tid >> 6;
  int l16 = lane & 15, quad = lane >> 4;
  int wm = wave >> 2, wn = wave & 3;
  long bm = blockIdx.x, bn = blockIdx.y;
  int z = blockIdx.z;

  int rl = l16 & 7;
  int c0 = 8 * (quad ^ rl);
  int c1 = 8 * ((quad ^ 4) ^ rl);
  int rowA = (wm * 64 + l16) * 64;
  int rowB = (wn * 32 + l16) * 64;

  int Lb = tid * 16;
  int Ls = Lb ^ (((Lb >> 7) & 7) << 4);
  int r_ = Ls >> 7, kin = (Ls & 127) >> 1;
  const u16* pA = A + (bm * 256 + r_) * (long)lda + kin + (long)z * K;
  const u16* pB = BT + (bn * 256 + r_) * (long)lda + kin + (long)z * K;

  f4 acc[4][4][2];
#pragma unroll
  for (int q = 0; q < 4; ++q)
#pragma unroll
    for (int mi = 0; mi < 4; ++mi)
#pragma unroll
      for (int nj = 0; nj < 2; ++nj) acc[q][mi][nj] = f4{0.f, 0.f, 0.f, 0.f};
  s8v aF[4][2], bF[2][2][2];

#define BAR asm volatile("s_barrier" ::: "memory")
#define LGK0 asm volatile("s_waitcnt lgkmcnt(0)" ::: "memory")
#define WVM4 asm volatile("s_waitcnt vmcnt(4)" ::: "memory")
#define WVM0 asm volatile("s_waitcnt vmcnt(0)" ::: "memory")

#define STAGE(mat, half, t, buf)                                               \
  do {                                                                         \
    const u16* g_ = ((mat) ? pB : pA) + (long)(half) * 128 * lda + (t) * 64;   \
    char* l_ = ((char*)S) + ((buf) * 32768 + (mat) * 16384 + (half) * 8192) * 2 + wave * 1024; \
    GLD_LDS16(g_, l_);                                                         \
    GLD_LDS16(g_ + 64 * (long)lda, l_ + 8192);                                 \
  } while (0)

#define LDA(buf, mh)                                                           \
  do {                                                                         \
    const u16* p_ = S + (buf) * 32768 + (mh) * 8192 + rowA;                    \
    _Pragma("unroll") for (int mi = 0; mi < 4; ++mi) {                         \
      aF[mi][0] = *(const s8v*)(p_ + mi * 1024 + c0);                          \
      aF[mi][1] = *(const s8v*)(p_ + mi * 1024 + c1);                          \
    }                                                                          \
  } while (0)

#define LDB(buf, nh, set)                                                      \
  do {                                                                         \
    const u16* p_ = S + (buf) * 32768 + 16384 + (nh) * 8192 + rowB;            \
    _Pragma("unroll") for (int nj = 0; nj < 2; ++nj) {                         \
      bF[set][nj][0] = *(const s8v*)(p_ + nj * 1024 + c0);                     \
      bF[set][nj][1] = *(const s8v*)(p_ + nj * 1024 + c1);                     \
    }                                                                          \
  } while (0)

#define MM(q)                                                                  \
  do {                                                                         \
    _Pragma("unroll") for (int mi = 0; mi < 4; ++mi)                           \
        _Pragma("unroll") for (int nj = 0; nj < 2; ++nj) {                     \
      acc[q][mi][nj] = __builtin_amdgcn_mfma_f32_16x16x32_bf16(                \
          aF[mi][0], bF[(q) & 1][nj][0], acc[q][mi][nj], 0, 0, 0);             \
      acc[q][mi][nj] = __builtin_amdgcn_mfma_f32_16x16x32_bf16(                \
          aF[mi][1], bF[(q) & 1][nj][1], acc[q][mi][nj], 0, 0, 0);             \
    }                                                                          \
  } while (0)

#define PHASES(t, LAST)                                                        \
  LDA(0, 0); LDB(0, 0, 0); STAGE(0, 1, (t) + 1, 1);                            \
  BAR; LGK0; __builtin_amdgcn_s_setprio(1); MM(0); __builtin_amdgcn_s_setprio(0); BAR; \
  LDB(0, 1, 1); STAGE(1, 1, (t) + 1, 1);                                       \
  BAR; LGK0; __builtin_amdgcn_s_setprio(1); MM(1); __builtin_amdgcn_s_setprio(0); BAR; \
  LDA(0, 1); if (!(LAST)) STAGE(0, 0, (t) + 2, 0);                             \
  BAR; LGK0; __builtin_amdgcn_s_setprio(1); MM(2); __builtin_amdgcn_s_setprio(0); BAR; \
  if (!(LAST)) STAGE(1, 0, (t) + 2, 0);                                        \
  __builtin_amdgcn_s_setprio(1); MM(3); __builtin_amdgcn_s_setprio(0);         \
  if (LAST) { WVM0; } else { WVM4; }                                           \
  BAR;                                                                         \
  LDA(1, 0); LDB(1, 0, 0); if (!(LAST)) STAGE(0, 1, (t) + 2, 0);               \
  BAR; LGK0; __builtin_amdgcn_s_setprio(1); MM(0); __builtin_amdgcn_s_setprio(0); BAR; \
  LDB(1, 1, 1); if (!(LAST)) STAGE(1, 1, (t) + 2, 0);                          \
  BAR; LGK0; __builtin_amdgcn_s_setprio(1); MM(1); __builtin_amdgcn_s_setprio(0); BAR; \
  LDA(1, 1); if (!(LAST)) STAGE(0, 0, (t) + 3, 1);                             \
  BAR; LGK0; __builtin_amdgcn_s_setprio(1); MM(2); __builtin_amdgcn_s_setprio(0); BAR; \
  if (!(LAST)) STAGE(1, 0, (t) + 3, 1);                                        \
  __builtin_amdgcn_s_setprio(1); MM(3); __builtin_amdgcn_s_setprio(0);         \
  if (!(LAST)) { WVM4; BAR; }

  STAGE(0, 0, 0, 0);
  STAGE(1, 0, 0, 0);
  STAGE(0, 1, 0, 0);
  STAGE(1, 1, 0, 0);
  STAGE(0, 0, 1, 1);
  STAGE(1, 0, 1, 1);
  WVM4; BAR;

  int NI = K >> 7;
  for (int i = 0; i < NI - 1; ++i) {
    int t = 2 * i;
    PHASES(t, 0);
  }
  {
    int t = 2 * (NI - 1);
    PHASES(t, 1);
  }

#undef PHASES
#undef MM
#undef LDB
#undef LDA
#undef STAGE
#undef WVM0
#undef WVM4
#undef LGK0
#undef BAR

  float* P0 = (EPI == 0) ? ((float*)outp + (long)z * M * N) : nullptr;
#pragma unroll
  for (int q = 0; q < 4; ++q) {
    int mh = q >> 1, nh = q & 1;
#pragma unroll
    for (int mi = 0; mi < 4; ++mi) {
#pragma unroll
      for (int nj = 0; nj < 2; ++nj) {
        long row = bm * 256 + mh * 128 + wm * 64 + mi * 16 + quad * 4;
        int col = (int)bn * 256 + nh * 128 + wn * 32 + nj * 16 + l16;
        float bcol = 0.f;
        if (EPI != 0) bcol = bias[col];
#pragma unroll
        for (int rr = 0; rr < 4; ++rr) {
          float val = acc[q][mi][nj][rr] + bcol;
          if (EPI == 0) {
            P0[(row + rr) * (long)N + col] = val;
          } else if (EPI == 1) {
            ((u16*)outp)[(row + rr) * (long)N + col] = f2b(val > 0.f ? val : 0.f);
          } else {
            ((float*)outp)[(row + rr) * (long)N + col] =
                resid[(row + rr) * (long)N + col] + val;
          }
        }
      }
    }
  }
}

// ---------------- 256x128 4-phase GEMM (new this round) ----------------
// A[M,K] bf16, BT[N,K] bf16, out fp32 = resid + A@B^T + bias. Grid (M/256, N/128).
// 512 threads = 8 waves as 4M x 2N, wave tile 64x64 (LDS-read:MFMA ratio 0.5,
// same ~60% ceiling as the 256x256 shape). LDS: 2 buf x {A0,A1,B} x [128][64] u16
// = 96 KiB. Same G4 3-bit XOR swizzle both sides (r3-verified: 0 conflicts).
// Phase structure per iter (tiles t->buf0, t+1->buf1), 16 MFMA per phase:
//   ph1: LDA(buf0)+LDB(buf0,nh0); STAGEB(t+1->buf1); BAR; LGK0; MM; BAR
//   ph2: LDB(buf0,nh1); STAGEA(t+2->buf0);           BAR; LGK0; MM; vmcnt(4); BAR
//   ph3: LDA(buf1)+LDB(buf1,nh0); STAGEB(t+2->buf0); BAR; LGK0; MM; BAR
//   ph4: LDB(buf1,nh1); STAGEA(t+3->buf1);           BAR; LGK0; MM; vmcnt(4); BAR
// FIFO ledger (A-stage=4 loads, B-stage=2): at ph2-end 10 outstanding, vmcnt(4)
// completes (t+1).A,(t+1).B (read ph3/ph4), leaves (t+2).A. At ph4-end completes
// (t+2).A,(t+2).B (read next ph1/ph2), leaves (t+3).A. Every overwrite >=2 barriers
// after the slot's last ds_read. Tail: keep ph1's B-stage, vmcnt(0) at ph2-end.
// Requires K >= 256 (NI >= 2).
__global__ __launch_bounds__(512) void k_gemm256n128(const u16* __restrict__ A,
                                                     const u16* __restrict__ BT,
                                                     const float* __restrict__ bias,
                                                     const float* __restrict__ resid,
                                                     float* __restrict__ outp,
                                                     int M, int N, int K, int lda) {
  __shared__ __align__(16) u16 S[49152];  // 96 KiB: [buf][A0|A1|B][128][64]
  int tid = threadIdx.x, lane = tid & 63, wave = tid >> 6;
  int l16 = lane & 15, quad = lane >> 4;
  int wm = wave >> 1, wn = wave & 1;
  long bm = blockIdx.x, bn = blockIdx.y;

  int rl = l16 & 7;
  int c0 = 8 * (quad ^ rl);
  int c1 = 8 * ((quad ^ 4) ^ rl);
  // A frag: block (wm>>1), row-in-block (wm&1)*64 + mi*16 + l16  (row&7 == l16&7)
  int rowA = (wm >> 1) * 8192 + ((wm & 1) * 64 + l16) * 64;
  // B frag: rows wn*64 + nh*32 + nj*16 + l16 in block at u16-offset 16384
  int rowB = 16384 + (wn * 64 + l16) * 64;

  int Lb = tid * 16;
  int Ls = Lb ^ (((Lb >> 7) & 7) << 4);
  int r_ = Ls >> 7, kin = (Ls & 127) >> 1;
  const u16* pA = A + (bm * 256 + r_) * (long)lda + kin;
  const u16* pB = BT + (bn * 128 + r_) * (long)lda + kin;

  f4 acc[4][4];  // [mi][nj], nj = nh*2 + nj2
#pragma unroll
  for (int mi = 0; mi < 4; ++mi)
#pragma unroll
    for (int nj = 0; nj < 4; ++nj) acc[mi][nj] = f4{0.f, 0.f, 0.f, 0.f};
  s8v aF[4][2], bF[2][2];

#define BAR asm volatile("s_barrier" ::: "memory")
#define LGK0 asm volatile("s_waitcnt lgkmcnt(0)" ::: "memory")
#define WVM4 asm volatile("s_waitcnt vmcnt(4)" ::: "memory")
#define WVM0 asm volatile("s_waitcnt vmcnt(0)" ::: "memory")

#define STAGEA(t, buf)                                                         \
  do {                                                                         \
    const u16* g_ = pA + (t) * 64;                                             \
    char* l_ = ((char*)S) + (buf) * 49152 + wave * 1024;                       \
    GLD_LDS16(g_, l_);                                                         \
    GLD_LDS16(g_ + 64 * (long)lda, l_ + 8192);                                 \
    GLD_LDS16(g_ + 128 * (long)lda, l_ + 16384);                               \
    GLD_LDS16(g_ + 192 * (long)lda, l_ + 24576);                               \
  } while (0)

#define STAGEB(t, buf)                                                         \
  do {                                                                         \
    const u16* g_ = pB + (t) * 64;                                             \
    char* l_ = ((char*)S) + (buf) * 49152 + 32768 + wave * 1024;               \
    GLD_LDS16(g_, l_);                                                         \
    GLD_LDS16(g_ + 64 * (long)lda, l_ + 8192);                                 \
  } while (0)

#define LDAn(buf)                                                              \
  do {                                                                         \
    const u16* p_ = S + (buf) * 24576 + rowA;                                  \
    _Pragma("unroll") for (int mi = 0; mi < 4; ++mi) {                         \
      aF[mi][0] = *(const s8v*)(p_ + mi * 1024 + c0);                          \
      aF[mi][1] = *(const s8v*)(p_ + mi * 1024 + c1);                          \
    }                                                                          \
  } while (0)

#define LDBn(buf, nh)                                                          \
  do {                                                                         \
    const u16* p_ = S + (buf) * 24576 + rowB + (nh) * 2048;                    \
    _Pragma("unroll") for (int nj2 = 0; nj2 < 2; ++nj2) {                      \
      bF[nj2][0] = *(const s8v*)(p_ + nj2 * 1024 + c0);                        \
      bF[nj2][1] = *(const s8v*)(p_ + nj2 * 1024 + c1);                        \
    }                                                                          \
  } while (0)

#define MMn(nh)                                                                \
  do {                                                                         \
    _Pragma("unroll") for (int mi = 0; mi < 4; ++mi)                           \
        _Pragma("unroll") for (int nj2 = 0; nj2 < 2; ++nj2) {                  \
      acc[mi][(nh) * 2 + nj2] = __builtin_amdgcn_mfma_f32_16x16x32_bf16(       \
          aF[mi][0], bF[nj2][0], acc[mi][(nh) * 2 + nj2], 0, 0, 0);            \
      acc[mi][(nh) * 2 + nj2] = __builtin_amdgcn_mfma_f32_16x16x32_bf16(       \
          aF[mi][1], bF[nj2][1], acc[mi][(nh) * 2 + nj2], 0, 0, 0);            \
    }                                                                          \
  } while (0)

#define PHASES(t, LAST)                                                        \
  /* ph1 */                                                                    \
  LDAn(0); LDBn(0, 0); STAGEB((t) + 1, 1);                                     \
  BAR; LGK0; __builtin_amdgcn_s_setprio(1); MMn(0); __builtin_amdgcn_s_setprio(0); BAR; \
  /* ph2 */                                                                    \
  LDBn(0, 1); if (!(LAST)) STAGEA((t) + 2, 0);                                 \
  BAR; LGK0; __builtin_amdgcn_s_setprio(1); MMn(1); __builtin_amdgcn_s_setprio(0); \
  if (LAST) { WVM0; } else { WVM4; }                                           \
  BAR;                                                                         \
  /* ph3 */                                                                    \
  LDAn(1); LDBn(1, 0); if (!(LAST)) STAGEB((t) + 2, 0);                        \
  BAR; LGK0; __builtin_amdgcn_s_setprio(1); MMn(0); __builtin_amdgcn_s_setprio(0); BAR; \
  /* ph4 */                                                                    \
  LDBn(1, 1); if (!(LAST)) STAGEA((t) + 3, 1);                                 \
  BAR; LGK0; __builtin_amdgcn_s_setprio(1); MMn(1); __builtin_amdgcn_s_setprio(0); \
  if (!(LAST)) { WVM4; }                                                       \
  BAR;

  // prologue: t0.A (4), t0.B (2), t1.A (4); vmcnt(4) completes t0.*, leaves t1.A
  STAGEA(0, 0);
  STAGEB(0, 0);
  STAGEA(1, 1);
  WVM4; BAR;

  int NI = K >> 7;  // 2 K-tiles of 64 per iteration
  for (int i = 0; i < NI - 1; ++i) {
    int t = 2 * i;
    PHASES(t, 0);
  }
  {
    int t = 2 * (NI - 1);
    PHASES(t, 1);
  }

#undef PHASES
#undef MMn
#undef LDBn
#undef LDAn
#undef STAGEB
#undef STAGEA
#undef WVM0
#undef WVM4
#undef LGK0
#undef BAR

  // epilogue: out = resid + acc + bias (fp32)
#pragma unroll
  for (int mi = 0; mi < 4; ++mi) {
#pragma unroll
    for (int nj = 0; nj < 4; ++nj) {
      long row = bm * 256 + wm * 64 + mi * 16 + quad * 4;
      int col = (int)bn * 128 + wn * 64 + nj * 16 + l16;
      float bcol = bias[col];
#pragma unroll
      for (int rr = 0; rr < 4; ++rr) {
        outp[(row + rr) * (long)N + col] =
            resid[(row + rr) * (long)N + col] + acc[mi][nj][rr] + bcol;
      }
    }
  }
}

extern "C" void kernel_launch(void* const* d_in, const int* in_sizes, int n_in, void* d_out,
                              int out_size, void* d_ws, size_t ws_size, hipStream_t stream) {
  const float* x = (const float*)d_in[0];
  const float* Wq = (const float*)d_in[1];
  const float* Wk = (const float*)d_in[2];
  const float* Wv = (const float*)d_in[3];
  const float* Wo = (const float*)d_in[4];
  const float* bo = (const float*)d_in[5];
  const float* W1 = (const float*)d_in[6];
  const float* b1 = (const float*)d_in[7];
  const float* W2 = (const float*)d_in[8];
  const float* b2 = (const float*)d_in[9];
  const float* g1 = (const float*)d_in[10];
  const float* be1 = (const float*)d_in[11];
  const float* g2 = (const float*)d_in[12];
  const float* be2 = (const float*)d_in[13];

  char* ws = (char*)d_ws;
  const size_t MB = 1ull << 20;
  u16* nx = (u16*)(ws + 0);            // 16 MB  LN1 out; reused as attn out
  u16* qb = (u16*)(ws + 16 * MB);      // 16 MB  q; reused as nx2
  u16* kb = (u16*)(ws + 32 * MB);      // 16 MB
  u16* vb = (u16*)(ws + 48 * MB);      // 16 MB
  float* x1 = (float*)(ws + 64 * MB);  // 32 MB  attn-sublayer output (fp32 residual)
  u16* h1 = (u16*)(ws + 96 * MB);      // 64 MB  MLP hidden (after attn)
  u16* vtr = (u16*)(ws + 96 * MB);     // 16 MB  V^T [B,H,D,S]; dead before h1 is written
  u16* WoT = (u16*)(ws + 160 * MB);    // 2 MB
  u16* W1T = (u16*)(ws + 162 * MB);    // 8 MB
  u16* W2T = (u16*)(ws + 170 * MB);    // 8 MB
  u16* WqT = (u16*)(ws + 178 * MB);
  u16* WkT = WqT + 64 * 64;
  u16* WvT = WkT + 64 * 64;
  u16* ob = nx;
  u16* nx2 = qb;

  k_transpose<<<dim3(32, 32), 256, 0, stream>>>(Wo, WoT, 1024, 1024);
  k_transpose<<<dim3(128, 32), 256, 0, stream>>>(W1, W1T, 1024, 4096);
  k_transpose<<<dim3(32, 128), 256, 0, stream>>>(W2, W2T, 4096, 1024);
  k_transpose<<<dim3(2, 2), 256, 0, stream>>>(Wq, WqT, 64, 64);
  k_transpose<<<dim3(2, 2), 256, 0, stream>>>(Wk, WkT, 64, 64);
  k_transpose<<<dim3(2, 2), 256, 0, stream>>>(Wv, WvT, 64, 64);

  k_layernorm<<<8192, 256, 0, stream>>>(x, g1, be1, nx);
  k_qkv<<<2048, 256, 0, stream>>>(nx, WqT, WkT, WvT, qb, kb, vb);
  k_vtrans<<<dim3(128, 16), 256, 0, stream>>>(vb, vtr);
  k_attn_mfma<<<dim3(128, 16), 256, 0, stream>>>(qb, kb, vtr, ob);
  k_gemm256n128<<<dim3(32, 8), 512, 0, stream>>>(ob, WoT, bo, x, x1, 8192, 1024, 1024, 1024);

  k_layernorm<<<8192, 256, 0, stream>>>(x1, g2, be2, nx2);
  k_gemm256<1><<<dim3(32, 16, 1), 512, 0, stream>>>(nx2, W1T, b1, nullptr, h1, 8192, 4096, 1024, 1024);
  k_gemm256n128<<<dim3(32, 8), 512, 0, stream>>>(h1, W2T, b2, x1, (float*)d_out, 8192, 1024, 4096, 4096);
}